// Round 3
// baseline (7413.617 us; speedup 1.0000x reference)
//
#include <hip/hip_runtime.h>

#define LRATE 1e-3f
static constexpr int Bn = 2048;
static constexpr int Dn = 784;
static constexpr int Hn = 256;
static constexpr int On = 10;
static constexpr int Cc = 64;           // chunk size
static constexpr int NCHUNK = Bn / Cc;  // 32

// LDS row strides (floats): multiples of 4 for aligned float4 (ds_read_b128)
static constexpr int AS = 68;   // 64x64 matrices
static constexpr int YS = 260;  // 64x256 matrices

// ---------------------------------------------------------------------------
// Kernel 1: whitening  xw[b,d] = sum_e (x[b,e]-mean[e]) * M[d,e]
// ---------------------------------------------------------------------------
__global__ __launch_bounds__(256) void whiten_kernel(
    const float* __restrict__ x, const float* __restrict__ mean,
    const float* __restrict__ Mw, float* __restrict__ xw)
{
  __shared__ __align__(16) float As[16][64];
  __shared__ __align__(16) float Bs[16][64];
  const int tid = threadIdx.x;
  const int b0 = blockIdx.x * 64;
  const int d0 = blockIdx.y * 64;
  const int mrow = tid >> 2;
  const int kq = (tid & 3) << 2;
  const int ty = tid >> 4, tx = tid & 15;

  float acc[4][4];
#pragma unroll
  for (int i = 0; i < 4; ++i)
#pragma unroll
    for (int j = 0; j < 4; ++j) acc[i][j] = 0.f;

  for (int k0 = 0; k0 < Dn; k0 += 16) {
    __syncthreads();
    {
      const float4 av = *(const float4*)&x[(b0 + mrow) * Dn + k0 + kq];
      const float4 mv = *(const float4*)&mean[k0 + kq];
      As[kq + 0][mrow] = av.x - mv.x;
      As[kq + 1][mrow] = av.y - mv.y;
      As[kq + 2][mrow] = av.z - mv.z;
      As[kq + 3][mrow] = av.w - mv.w;
      float4 bv = make_float4(0.f, 0.f, 0.f, 0.f);
      if (d0 + mrow < Dn) bv = *(const float4*)&Mw[(d0 + mrow) * Dn + k0 + kq];
      Bs[kq + 0][mrow] = bv.x;
      Bs[kq + 1][mrow] = bv.y;
      Bs[kq + 2][mrow] = bv.z;
      Bs[kq + 3][mrow] = bv.w;
    }
    __syncthreads();
#pragma unroll
    for (int k = 0; k < 16; ++k) {
      const float4 a = *(const float4*)&As[k][ty << 2];
      const float4 b = *(const float4*)&Bs[k][tx << 2];
      acc[0][0] += a.x * b.x; acc[0][1] += a.x * b.y; acc[0][2] += a.x * b.z; acc[0][3] += a.x * b.w;
      acc[1][0] += a.y * b.x; acc[1][1] += a.y * b.y; acc[1][2] += a.y * b.z; acc[1][3] += a.y * b.w;
      acc[2][0] += a.z * b.x; acc[2][1] += a.z * b.y; acc[2][2] += a.z * b.z; acc[2][3] += a.z * b.w;
      acc[3][0] += a.w * b.x; acc[3][1] += a.w * b.y; acc[3][2] += a.w * b.z; acc[3][3] += a.w * b.w;
    }
  }
  const int col = d0 + (tx << 2);
  if (col < Dn) {
#pragma unroll
    for (int i = 0; i < 4; ++i) {
      const int row = b0 + (ty << 2) + i;
      *(float4*)&xw[row * Dn + col] =
          make_float4(acc[i][0], acc[i][1], acc[i][2], acc[i][3]);
    }
  }
}

// ---------------------------------------------------------------------------
// Kernel 2: per-chunk Gram blocks  S_c = X_c X_c^T   (all chunks, parallel)
// ---------------------------------------------------------------------------
__global__ __launch_bounds__(256) void sgram_kernel(
    const float* __restrict__ xw, float* __restrict__ S_all)
{
  __shared__ __align__(16) float Xs[64 * 396];  // 64 x 392 staged (stride 396)
  const int t = threadIdx.x;
  const int c = blockIdx.x;
  const float* xc = xw + (size_t)c * Cc * Dn;
  const int ti = t >> 4, tj = t & 15;
  float acc[4][4];
#pragma unroll
  for (int a = 0; a < 4; ++a)
#pragma unroll
    for (int b = 0; b < 4; ++b) acc[a][b] = 0.f;

  for (int pass = 0; pass < 2; ++pass) {
    __syncthreads();
    for (int e4 = t; e4 < 64 * 98; e4 += 256) {
      const int r = e4 / 98, c4 = e4 - r * 98;
      *(float4*)&Xs[r * 396 + 4 * c4] =
          *(const float4*)&xc[r * Dn + pass * 392 + 4 * c4];
    }
    __syncthreads();
    for (int k4 = 0; k4 < 98; ++k4) {
      float4 A[4], Bv[4];
#pragma unroll
      for (int a = 0; a < 4; ++a) A[a] = *(const float4*)&Xs[(4 * ti + a) * 396 + 4 * k4];
#pragma unroll
      for (int b = 0; b < 4; ++b) Bv[b] = *(const float4*)&Xs[(4 * tj + b) * 396 + 4 * k4];
#pragma unroll
      for (int a = 0; a < 4; ++a)
#pragma unroll
        for (int b = 0; b < 4; ++b)
          acc[a][b] += A[a].x * Bv[b].x + A[a].y * Bv[b].y + A[a].z * Bv[b].z + A[a].w * Bv[b].w;
    }
  }
  float* Sc = S_all + (size_t)c * Cc * Cc;
#pragma unroll
  for (int a = 0; a < 4; ++a)
#pragma unroll
    for (int b = 0; b < 4; ++b)
      Sc[(4 * ti + a) * Cc + 4 * tj + b] = acc[a][b];
}

// ---------------------------------------------------------------------------
// Kernel 3 (per chunk): yhat[r][h] = sum_d X_c[r][d] * W[h][d]   [64 x 256]
// ---------------------------------------------------------------------------
__global__ __launch_bounds__(256) void yhat_kernel(
    const float* __restrict__ xc, const float* __restrict__ W,
    float* __restrict__ yhat)
{
  const int t = threadIdx.x;
  const int r = t & 63, hh = t >> 6;
  const int h = blockIdx.x * 4 + hh;
  const float4* xr = (const float4*)&xc[r * Dn];
  const float4* wr = (const float4*)&W[h * Dn];
  float acc = 0.f;
#pragma unroll 4
  for (int f = 0; f < 196; ++f) {
    const float4 a = xr[f], b = wr[f];
    acc += a.x * b.x + a.y * b.y + a.z * b.z + a.w * b.w;
  }
  yhat[r * Hn + h] = acc;
}

// ---------------------------------------------------------------------------
// Kernel 4 (per chunk): the small sequential recurrence.
// Prologue (T = yh yh^T) + epilogue (feats = alpha*yh) use all 256 threads;
// the 64 sequential steps run on ONE wave (lane k owns index k), vectors in
// registers, LDS bounce buffers for cross-lane broadcast, ZERO barriers.
// alpha/beta are unit-lower-triangular (zero-padded => full-width sums exact).
// ---------------------------------------------------------------------------
__global__ __launch_bounds__(256, 1) void seq_kernel(
    const float* __restrict__ yhat_g, const float* __restrict__ S_g,
    float* __restrict__ feats_c, float* __restrict__ beta_g)
{
  __shared__ __align__(16) float yh[64 * YS];
  __shared__ __align__(16) float Ts[64 * AS];
  __shared__ __align__(16) float Ss[64 * AS];
  __shared__ __align__(16) float al[64 * AS];
  __shared__ __align__(16) float be[64 * AS];
  __shared__ __align__(16) float qs[64 * AS];
  __shared__ __align__(16) float dbuf[AS];
  __shared__ __align__(16) float pbuf[AS];
  __shared__ __align__(16) float vbuf[AS];

  const int t = threadIdx.x;
  const int k = t >> 2;       // epilogue row
  const int qr = t & 3;       // epilogue quarter
  const int m0 = qr * 16;

  // ---- prologue: zero + load ----
  for (int e = t; e < 64 * AS; e += 256) { al[e] = 0.f; be[e] = 0.f; qs[e] = 0.f; }
  for (int e = t; e < Cc * Cc; e += 256)
    Ss[(e >> 6) * AS + (e & 63)] = S_g[e];
  for (int e4 = t; e4 < 64 * 64; e4 += 256) {  // 64*256 floats = 4096 float4
    const int r = e4 >> 6, c4 = e4 & 63;
    *(float4*)&yh[r * YS + 4 * c4] = ((const float4*)yhat_g)[e4];
  }
  __syncthreads();
  if (t < 64) { al[t * AS + t] = 1.f; be[t * AS + t] = 1.f; }
  // T = yh * yh^T  (16x16 thread grid, 4x4 blocks)
  {
    const int ti = t >> 4, tj = t & 15;
    float acc[4][4];
#pragma unroll
    for (int a = 0; a < 4; ++a)
#pragma unroll
      for (int b = 0; b < 4; ++b) acc[a][b] = 0.f;
    for (int k4 = 0; k4 < 64; ++k4) {
      float4 A[4], Bv[4];
#pragma unroll
      for (int a = 0; a < 4; ++a) A[a] = *(const float4*)&yh[(4 * ti + a) * YS + 4 * k4];
#pragma unroll
      for (int b = 0; b < 4; ++b) Bv[b] = *(const float4*)&yh[(4 * tj + b) * YS + 4 * k4];
#pragma unroll
      for (int a = 0; a < 4; ++a)
#pragma unroll
        for (int b = 0; b < 4; ++b)
          acc[a][b] += A[a].x * Bv[b].x + A[a].y * Bv[b].y + A[a].z * Bv[b].z + A[a].w * Bv[b].w;
    }
#pragma unroll
    for (int a = 0; a < 4; ++a)
#pragma unroll
      for (int b = 0; b < 4; ++b)
        Ts[(4 * ti + a) * AS + 4 * tj + b] = acc[a][b];
  }
  __syncthreads();

  // ---- the 64 sequential steps: single wave, no barriers ----
  if (t < 64) {
    const int lane = t;
    const float* arow = &al[lane * AS];
    const float* brow = &be[lane * AS];
    const float* qrow = &qs[lane * AS];
    for (int i = 0; i < Cc; ++i) {
      const float* trow = &Ts[i * AS];
      // P1: h = al[lane,:] . T[i,:]   (T row broadcast, al row per-lane)
      float a0 = 0.f, a1 = 0.f, a2 = 0.f, a3 = 0.f;
#pragma unroll
      for (int f = 0; f < 16; ++f) {
        const float4 av = ((const float4*)arow)[f];
        const float4 tv = ((const float4*)trow)[f];
        a0 += av.x * tv.x; a1 += av.y * tv.y; a2 += av.z * tv.z; a3 += av.w * tv.w;
      }
      const float h = (a0 + a1) + (a2 + a3);
      // P2: d = S[i,lane]-h ; p = be[lane,:] . d
      const float d = Ss[i * AS + lane] - h;
      dbuf[lane] = d;
      float p0 = 0.f, p1 = 0.f, p2 = 0.f, p3 = 0.f;
#pragma unroll
      for (int f = 0; f < 16; ++f) {
        const float4 bv = ((const float4*)brow)[f];
        const float4 dv = ((const float4*)dbuf)[f];
        p0 += bv.x * dv.x; p1 += bv.y * dv.y; p2 += bv.z * dv.z; p3 += bv.w * dv.w;
      }
      const float p = (p0 + p1) + (p2 + p3);
      pbuf[lane] = p;
      // P3a: r_m = sum_j p_j al[j][m]  (column gather, 2-way-free banks)
      // P3b: g_k = sum_j p_j q[k][j]   (row read, pbuf broadcast)
      float r0 = 0.f, r1 = 0.f, r2 = 0.f, r3 = 0.f;
      float g0 = 0.f, g1 = 0.f, g2 = 0.f, g3 = 0.f;
#pragma unroll
      for (int j4 = 0; j4 < 16; ++j4) {
        const float4 pv = ((const float4*)pbuf)[j4];
        r0 += pv.x * al[(4 * j4 + 0) * AS + lane];
        r1 += pv.y * al[(4 * j4 + 1) * AS + lane];
        r2 += pv.z * al[(4 * j4 + 2) * AS + lane];
        r3 += pv.w * al[(4 * j4 + 3) * AS + lane];
        const float4 qv = ((const float4*)qrow)[j4];
        g0 += pv.x * qv.x; g1 += pv.y * qv.y; g2 += pv.z * qv.z; g3 += pv.w * qv.w;
      }
      const float r = (r0 + r1) + (r2 + r3);
      const float g = (g0 + g1) + (g2 + g3);
      const float v = h + LRATE * g;
      if (lane < i) al[i * AS + lane] = LRATE * r;
      vbuf[lane] = (lane < i) ? v : 0.f;
      if (lane < i) { qs[lane * AS + i] = v; qs[i * AS + lane] = v; }
      // diag: q[i][i] = T[i][i] + LR * sum_{j<i} p_j (h_j + v_j)
      float z = (lane < i) ? p * (h + v) : 0.f;
      z += __shfl_xor(z, 1);  z += __shfl_xor(z, 2);  z += __shfl_xor(z, 4);
      z += __shfl_xor(z, 8);  z += __shfl_xor(z, 16); z += __shfl_xor(z, 32);
      if (lane == i) qs[i * AS + i] = Ts[i * AS + i] + LRATE * z;
      // P4a: be[i][m] = -LR * sum_{j<i} v_j be[j][m]  (vbuf value-masked)
      float u0 = 0.f, u1 = 0.f, u2 = 0.f, u3 = 0.f;
#pragma unroll
      for (int j4 = 0; j4 < 16; ++j4) {
        const float4 vv = ((const float4*)vbuf)[j4];
        u0 += vv.x * be[(4 * j4 + 0) * AS + lane];
        u1 += vv.y * be[(4 * j4 + 1) * AS + lane];
        u2 += vv.z * be[(4 * j4 + 2) * AS + lane];
        u3 += vv.w * be[(4 * j4 + 3) * AS + lane];
      }
      if (lane < i) be[i * AS + lane] = -LRATE * ((u0 + u1) + (u2 + u3));
    }
  }
  __syncthreads();

  // ---- epilogue: beta -> global; Y = alpha * yhat -> feats ----
  for (int e4 = t; e4 < 1024; e4 += 256) {  // 64*64 floats
    const int r = e4 >> 4, c4 = e4 & 15;
    ((float4*)beta_g)[e4] = *(const float4*)&be[r * AS + 4 * c4];
  }
  {
    const int r = k;  // t>>2
    float4 a4[16];
#pragma unroll
    for (int f = 0; f < 16; ++f) a4[f] = *(const float4*)&al[r * AS + 4 * f];
    float4 acc[16];
#pragma unroll
    for (int f = 0; f < 16; ++f) acc[f] = make_float4(0.f, 0.f, 0.f, 0.f);
#pragma unroll
    for (int m4 = 0; m4 < 16; ++m4) {
      const float4 av = a4[m4];
      const float4* y0 = (const float4*)&yh[(4 * m4 + 0) * YS + m0 * 4];
      const float4* y1 = (const float4*)&yh[(4 * m4 + 1) * YS + m0 * 4];
      const float4* y2 = (const float4*)&yh[(4 * m4 + 2) * YS + m0 * 4];
      const float4* y3 = (const float4*)&yh[(4 * m4 + 3) * YS + m0 * 4];
#pragma unroll
      for (int f = 0; f < 16; ++f) {
        const float4 v0 = y0[f], v1 = y1[f], v2 = y2[f], v3 = y3[f];
        acc[f].x += av.x * v0.x + av.y * v1.x + av.z * v2.x + av.w * v3.x;
        acc[f].y += av.x * v0.y + av.y * v1.y + av.z * v2.y + av.w * v3.y;
        acc[f].z += av.x * v0.z + av.y * v1.z + av.z * v2.z + av.w * v3.z;
        acc[f].w += av.x * v0.w + av.y * v1.w + av.z * v2.w + av.w * v3.w;
      }
    }
    float4* dst = (float4*)&feats_c[r * Hn + m0 * 4];  // h-range [qr*64, qr*64+64)
#pragma unroll
    for (int f = 0; f < 16; ++f) dst[f] = acc[f];
  }
}

// ---------------------------------------------------------------------------
// Kernel 5 (per chunk): V = X_c - Y W ; U = beta V ; W += LR * Y^T U.
// grid 98 WGs, each owns 8 consecutive W columns.
// ---------------------------------------------------------------------------
__global__ __launch_bounds__(256, 1) void upd_kernel(
    const float* __restrict__ xc, const float* __restrict__ Yg,
    const float* __restrict__ beta_g, float* __restrict__ W)
{
  __shared__ __align__(16) float Yl[64 * YS];
  __shared__ __align__(16) float bl[64 * AS];
  __shared__ __align__(16) float WlT[8 * YS];
  __shared__ __align__(16) float XT[8 * 64];
  __shared__ __align__(16) float VT[8 * 64];
  __shared__ __align__(16) float UT[8 * 64];
  const int t = threadIdx.x;
  const int d0 = blockIdx.x * 8;

  {  // load Y
    const int r = t >> 2, qr = t & 3;
    const float4* src = (const float4*)&Yg[r * Hn + qr * 64];
    float4* dst = (float4*)&Yl[r * YS + qr * 64];
#pragma unroll
    for (int f = 0; f < 16; ++f) dst[f] = src[f];
  }
#pragma unroll
  for (int f = 0; f < 4; ++f) {  // load beta
    const int e4 = t + 256 * f;
    const int r = e4 >> 4, c4 = e4 & 15;
    *(float4*)&bl[r * AS + 4 * c4] = ((const float4*)beta_g)[e4];
  }
  {  // load W slice (transposed)
    const float4* wsrc = (const float4*)&W[t * Dn + d0];
    const float4 w0 = wsrc[0], w1 = wsrc[1];
    WlT[0 * YS + t] = w0.x; WlT[1 * YS + t] = w0.y; WlT[2 * YS + t] = w0.z; WlT[3 * YS + t] = w0.w;
    WlT[4 * YS + t] = w1.x; WlT[5 * YS + t] = w1.y; WlT[6 * YS + t] = w1.z; WlT[7 * YS + t] = w1.w;
  }
  if (t < 64) {  // load X slice (transposed)
    const float4* xsrc = (const float4*)&xc[t * Dn + d0];
    const float4 x0 = xsrc[0], x1 = xsrc[1];
    XT[0 * 64 + t] = x0.x; XT[1 * 64 + t] = x0.y; XT[2 * 64 + t] = x0.z; XT[3 * 64 + t] = x0.w;
    XT[4 * 64 + t] = x1.x; XT[5 * 64 + t] = x1.y; XT[6 * 64 + t] = x1.z; XT[7 * 64 + t] = x1.w;
  }
  __syncthreads();
  const int r = t & 63, da = t >> 6, db = da + 4;
  {  // V = X - Y W
    float va = XT[da * 64 + r], vb = XT[db * 64 + r];
    const float4* yrow = (const float4*)&Yl[r * YS];
    const float4* wa = (const float4*)&WlT[da * YS];
    const float4* wb = (const float4*)&WlT[db * YS];
#pragma unroll 8
    for (int f = 0; f < 64; ++f) {
      const float4 y = yrow[f], A = wa[f], Bv = wb[f];
      va -= y.x * A.x + y.y * A.y + y.z * A.z + y.w * A.w;
      vb -= y.x * Bv.x + y.y * Bv.y + y.z * Bv.z + y.w * Bv.w;
    }
    VT[da * 64 + r] = va; VT[db * 64 + r] = vb;
  }
  __syncthreads();
  {  // U = beta V
    float ua = 0.f, ub = 0.f;
    const float4* br = (const float4*)&bl[r * AS];
    const float4* vta = (const float4*)&VT[da * 64];
    const float4* vtb = (const float4*)&VT[db * 64];
#pragma unroll
    for (int f = 0; f < 16; ++f) {
      const float4 b = br[f], A = vta[f], Bv = vtb[f];
      ua += b.x * A.x + b.y * A.y + b.z * A.z + b.w * A.w;
      ub += b.x * Bv.x + b.y * Bv.y + b.z * Bv.z + b.w * Bv.w;
    }
    UT[da * 64 + r] = ua; UT[db * 64 + r] = ub;
  }
  __syncthreads();
  {  // W[h=t][d0+dj] += LR * sum_r Y[r][h] * U[r][dj]
    float wacc[8];
#pragma unroll
    for (int dj = 0; dj < 8; ++dj) wacc[dj] = 0.f;
    for (int r4 = 0; r4 < 16; ++r4) {
      float4 u[8];
#pragma unroll
      for (int dj = 0; dj < 8; ++dj) u[dj] = *(const float4*)&UT[dj * 64 + 4 * r4];
      const float y0 = Yl[(4 * r4 + 0) * YS + t];
      const float y1 = Yl[(4 * r4 + 1) * YS + t];
      const float y2 = Yl[(4 * r4 + 2) * YS + t];
      const float y3 = Yl[(4 * r4 + 3) * YS + t];
#pragma unroll
      for (int dj = 0; dj < 8; ++dj)
        wacc[dj] += y0 * u[dj].x + y1 * u[dj].y + y2 * u[dj].z + y3 * u[dj].w;
    }
    float4 o0, o1;
    o0.x = WlT[0 * YS + t] + LRATE * wacc[0];
    o0.y = WlT[1 * YS + t] + LRATE * wacc[1];
    o0.z = WlT[2 * YS + t] + LRATE * wacc[2];
    o0.w = WlT[3 * YS + t] + LRATE * wacc[3];
    o1.x = WlT[4 * YS + t] + LRATE * wacc[4];
    o1.y = WlT[5 * YS + t] + LRATE * wacc[5];
    o1.z = WlT[6 * YS + t] + LRATE * wacc[6];
    o1.w = WlT[7 * YS + t] + LRATE * wacc[7];
    float4* wdst = (float4*)&W[t * Dn + d0];
    wdst[0] = o0; wdst[1] = o1;
  }
}

// ---------------------------------------------------------------------------
// Kernel 6: logits = relu(feats) @ R^T + bias
// ---------------------------------------------------------------------------
__global__ __launch_bounds__(256) void readout_kernel(
    const float* __restrict__ feats, const float* __restrict__ R,
    const float* __restrict__ bias, float* __restrict__ out)
{
  const int g = blockIdx.x * 256 + threadIdx.x;
  if (g >= Bn * On) return;
  const int b = g / On;
  const int o = g - b * On;
  const float* f = feats + b * Hn;
  const float* r = R + o * Hn;
  float acc = bias[o];
#pragma unroll 8
  for (int h = 0; h < Hn; ++h) acc += fmaxf(f[h], 0.f) * r[h];
  out[g] = acc;
}

// ---------------------------------------------------------------------------
extern "C" void kernel_launch(void* const* d_in, const int* in_sizes, int n_in,
                              void* d_out, int out_size, void* d_ws, size_t ws_size,
                              hipStream_t stream) {
  const float* x    = (const float*)d_in[0];  // [2048,784]
  const float* mean = (const float*)d_in[1];  // [784]
  const float* Mw   = (const float*)d_in[2];  // [784,784]
  const float* W0   = (const float*)d_in[3];  // [256,784]
  const float* R    = (const float*)d_in[4];  // [10,256]
  const float* bias = (const float*)d_in[5];  // [10]
  float* out = (float*)d_out;                 // [2048,10]

  float* p = (float*)d_ws;
  float* xw     = p;  p += (size_t)Bn * Dn;        // 1,605,632
  float* feats  = p;  p += (size_t)Bn * Hn;        //   524,288
  float* W_dyn  = p;  p += (size_t)Hn * Dn;        //   200,704
  float* S_all  = p;  p += (size_t)NCHUNK * Cc * Cc; // 131,072
  float* yhat   = p;  p += (size_t)Cc * Hn;        //    16,384
  float* beta_g = p;  p += (size_t)Cc * Cc;        //     4,096
  (void)ws_size; (void)n_in; (void)in_sizes; (void)out_size;

  whiten_kernel<<<dim3(Bn / 64, (Dn + 63) / 64), 256, 0, stream>>>(x, mean, Mw, xw);
  sgram_kernel<<<NCHUNK, 256, 0, stream>>>(xw, S_all);
  hipMemcpyAsync(W_dyn, W0, (size_t)Hn * Dn * sizeof(float),
                 hipMemcpyDeviceToDevice, stream);

  for (int c = 0; c < NCHUNK; ++c) {
    const float* xc = xw + (size_t)c * Cc * Dn;
    float* feats_c  = feats + (size_t)c * Cc * Hn;
    yhat_kernel<<<64, 256, 0, stream>>>(xc, W_dyn, yhat);
    seq_kernel<<<1, 256, 0, stream>>>(yhat, S_all + (size_t)c * Cc * Cc,
                                      feats_c, beta_g);
    upd_kernel<<<98, 256, 0, stream>>>(xc, feats_c, beta_g, W_dyn);
  }

  readout_kernel<<<(Bn * On + 255) / 256, 256, 0, stream>>>(feats, R, bias, out);
}